// Round 4
// baseline (3161.217 us; speedup 1.0000x reference)
//
#include <hip/hip_runtime.h>
#include <math.h>

// Problem constants
#define T_STEPS 256
#define BATCH   256
#define HID     512
#define DIN     640     // P*F = 5*128
#define NCOL    2048    // 4*H
#define NCLASS  60
#define KSTEPS  36      // 1152 / 32
#define KX      20      // x-part k-steps (640/32)
#define KH      16      // h-part k-steps (512/32)

typedef float f32x4 __attribute__((ext_vector_type(4)));
typedef short s16x8 __attribute__((ext_vector_type(8)));

// ws layout (bytes):
//   [0,       1024)      barrier counters (8 groups, 128 B apart)
//   [1024,    4719616)   Wf  bf16 packed weights (128*36*64*8 shorts)
//   [4719616, 4981760)   hb0 bf16 h frag buffer
//   [4981760, 5243904)   hb1 bf16 h frag buffer
//   [5243904, 5768192)   hplain fp32 (256x512)
//   [5768192, 274203648) gxp bf16 precomputed x@Wx   (fast path only)
#define WF_OFF   1024
#define HB0_OFF  4719616
#define HB1_OFF  4981760
#define HPL_OFF  5243904
#define GX_OFF   5768192
#define WS_NEED  274203648ULL

__device__ __forceinline__ unsigned short f2bf(float x) {
    union { float f; unsigned u; } v; v.f = x;
    unsigned r = v.u + 0x7fffu + ((v.u >> 16) & 1u);   // round-to-nearest-even
    return (unsigned short)(r >> 16);
}

__device__ __forceinline__ s16x8 pack8(float4 a, float4 b) {
    s16x8 r;
    r[0] = (short)f2bf(a.x); r[1] = (short)f2bf(a.y);
    r[2] = (short)f2bf(a.z); r[3] = (short)f2bf(a.w);
    r[4] = (short)f2bf(b.x); r[5] = (short)f2bf(b.y);
    r[6] = (short)f2bf(b.z); r[7] = (short)f2bf(b.w);
    return r;
}

// ---------------------------------------------------------------------------
// Pack [Wx; Wh] (1152 x 2048 fp32) into bf16 B-fragment-linear layout:
//   Wf[nb][ks][lane][8], nb = hg*4 + gate; col n = gate*512 + hg*16 + (lane&15)
//   k = ks*32 + (lane>>4)*8 + j
// ---------------------------------------------------------------------------
__global__ __launch_bounds__(256) void pack_w_kernel(
    const float* __restrict__ Wx, const float* __restrict__ Wh,
    unsigned short* __restrict__ Wf)
{
    int g = blockIdx.x * 256 + threadIdx.x;      // [0, 128*36*64)
    int nb  = g / (KSTEPS * 64);
    int rem = g - nb * (KSTEPS * 64);
    int ks = rem >> 6;
    int lane = rem & 63;
    int gate = nb & 3, hg = nb >> 2;
    int n = gate * 512 + hg * 16 + (lane & 15);
    int kbase = ks * 32 + (lane >> 4) * 8;
    s16x8 frag;
    #pragma unroll
    for (int j = 0; j < 8; j++) {
        int k = kbase + j;
        float v = (k < DIN) ? Wx[(size_t)k * NCOL + n]
                            : Wh[(size_t)(k - DIN) * NCOL + n];
        frag[j] = (short)f2bf(v);
    }
    *(s16x8*)(Wf + (size_t)g * 8) = frag;
}

// ---------------------------------------------------------------------------
// gx = x @ Wx for all timesteps (feed-forward, fully parallel).
// Grid: bid = ((t*4 + mtile)*32) + hg; WG = 64 rows x 64 gate-cols, K=640.
// Output layout (bf16): gxp[((t*256 + row)*32 + hg)*64 + (gate*16 + j)]
// -> each consumer WG reads a private, contiguous 4 KB block per step.
// ---------------------------------------------------------------------------
__global__ __launch_bounds__(256) void gx_kernel(
    const float* __restrict__ x,
    const unsigned short* __restrict__ Wf,
    unsigned short* __restrict__ gxp)
{
    __shared__ float gl[64][65];
    int tid = threadIdx.x;
    int lane = tid & 63, w = tid >> 6;
    int wm = w & 1, wn = w >> 1;
    int hg    = blockIdx.x & 31;
    int mtile = (blockIdx.x >> 5) & 3;
    int t     = blockIdx.x >> 7;
    int quad = lane >> 4, l16 = lane & 15;
    int r0 = mtile * 64 + wm * 32 + l16;
    int r1 = r0 + 16;

    f32x4 acc00 = {0.f,0.f,0.f,0.f}, acc01 = acc00, acc10 = acc00, acc11 = acc00;
    const unsigned short* wf0 = Wf + (((size_t)(hg * 4 + wn * 2) * KSTEPS) * 64 + lane) * 8;
    const unsigned short* wf1 = wf0 + (size_t)KSTEPS * 64 * 8;

    #pragma unroll 4
    for (int ks = 0; ks < KX; ks++) {
        int k = ks * 32 + quad * 8;
        int p = k >> 7, f = k & 127;
        const float* s0 = x + ((size_t)(r0 * 5 + p) * 256 + t) * 128 + f;
        const float* s1 = x + ((size_t)(r1 * 5 + p) * 256 + t) * 128 + f;
        float4 u0 = *(const float4*)s0;
        float4 u1 = *(const float4*)(s0 + 4);
        float4 v0 = *(const float4*)s1;
        float4 v1 = *(const float4*)(s1 + 4);
        s16x8 a0 = pack8(u0, u1);
        s16x8 a1 = pack8(v0, v1);
        s16x8 b0 = *(const s16x8*)(wf0 + (size_t)ks * 64 * 8);
        s16x8 b1 = *(const s16x8*)(wf1 + (size_t)ks * 64 * 8);
        acc00 = __builtin_amdgcn_mfma_f32_16x16x32_bf16(a0, b0, acc00, 0, 0, 0);
        acc10 = __builtin_amdgcn_mfma_f32_16x16x32_bf16(a1, b0, acc10, 0, 0, 0);
        acc01 = __builtin_amdgcn_mfma_f32_16x16x32_bf16(a0, b1, acc01, 0, 0, 0);
        acc11 = __builtin_amdgcn_mfma_f32_16x16x32_bf16(a1, b1, acc11, 0, 0, 0);
    }

    int colb = wn * 32 + l16;
    int rowb = wm * 32 + quad * 4;
    #pragma unroll
    for (int r = 0; r < 4; r++) {
        gl[rowb + r][colb]           = acc00[r];
        gl[rowb + r][colb + 16]      = acc01[r];
        gl[rowb + 16 + r][colb]      = acc10[r];
        gl[rowb + 16 + r][colb + 16] = acc11[r];
    }
    __syncthreads();

    #pragma unroll
    for (int pass = 0; pass < 2; pass++) {
        int row = (tid >> 3) + pass * 32;
        int seg = (tid & 7) * 8;
        s16x8 o;
        #pragma unroll
        for (int j = 0; j < 8; j++) o[j] = (short)f2bf(gl[row][seg + j]);
        size_t R = (size_t)mtile * 64 + row;
        *(s16x8*)(gxp + (((size_t)t * 256 + R) * 32 + hg) * 64 + seg) = o;
    }
}

// ---------------------------------------------------------------------------
// FAST-PATH persistent recurrence: only h @ Wh per step (K=512).
// 256 WGs x 256 thr, 1 WG/CU. WG = (mt = bid&7, hg = bid>>3).
// LDS: Wh frags 64 KB + h-stage 32 KB + gates tile 8.3 KB.
// Per step: gx prefetch (cached) -> group barrier -> cooperative uncached
// h gather into LDS (4096 x 8 B reqs, deduped) -> MFMA -> epilogue -> publish.
// ---------------------------------------------------------------------------
__global__ __launch_bounds__(256, 1) void plstm_persist2(
    const unsigned short* __restrict__ gxp,
    const unsigned short* __restrict__ Wf,
    unsigned short* __restrict__ hb0,
    unsigned short* __restrict__ hb1,
    float* __restrict__ hplain,
    const float* __restrict__ bias,
    const float* __restrict__ tau,
    const float* __restrict__ shift,
    int* __restrict__ cnt)
{
    __shared__ unsigned short wfl[4 * KH * 64 * 8];   // 65536 B (Wh frags)
    __shared__ unsigned long long hst[4096];          // 32768 B (h slice)
    __shared__ float gl[32][65];                      // 8320 B

    int tid = threadIdx.x;
    int lane = tid & 63, w = tid >> 6;
    int mt = blockIdx.x & 7, hg = blockIdx.x >> 3;
    int quad = lane >> 4, l16 = lane & 15;
    int mb = w & 1;
    int n0 = (w >> 1) * 2;

    // --- stage Wh frag slice (ks = KX..KX+15 of this hg's 4 nb) into LDS ---
    {
        s16x8* dst = (s16x8*)wfl;
        const s16x8* wfb = (const s16x8*)Wf;
        #pragma unroll
        for (int r2 = 0; r2 < 16; r2++) {
            int fi = r2 * 256 + tid;              // [0, 4096)
            int nb_l = fi >> 10;
            int khs  = (fi >> 6) & 15;
            int ln   = fi & 63;
            dst[fi] = wfb[((size_t)(hg * 4 + nb_l) * KSTEPS + KX + khs) * 64 + ln];
        }
    }

    // --- per-thread epilogue constants + register state (2 cells) ---
    int b_l = tid >> 3;
    int j0  = (tid & 7) * 2;
    int bG  = mt * 32 + b_l;
    int jG0 = hg * 16 + j0;
    float bi[2], bff[2], bg[2], bo[2], tj[2], sj[2];
    #pragma unroll
    for (int r = 0; r < 2; r++) {
        int jG = jG0 + r;
        bi[r] = bias[jG];        bff[r] = bias[512 + jG];
        bg[r] = bias[1024 + jG]; bo[r] = bias[1536 + jG];
        tj[r] = tau[jG];         sj[r] = shift[jG];
    }
    float creg[2] = {0.f, 0.f}, hreg[2] = {0.f, 0.f};
    size_t pub32;
    {
        int mb2 = bG >> 4, khs2 = jG0 >> 5;
        int ln  = (bG & 15) + ((jG0 >> 3) & 3) * 16;
        pub32 = ((((size_t)mb2 * KH + khs2) * 64 + ln) * 8 + (jG0 & 7)) >> 1;
    }
    __syncthreads();

    int* mycnt = cnt + mt * 32;
    const unsigned short* hsl = (const unsigned short*)hst + (size_t)mb * 16 * 64 * 8;

    for (int t = 0; t < T_STEPS; t++) {
        // ---- gx prefetch: private, contiguous, normal cached loads ----
        const unsigned* gb = (const unsigned*)(gxp + (((size_t)t * 256 + bG) * 32 + hg) * 64);
        unsigned gxr0 = gb[ 0 + (tid & 7)];
        unsigned gxr1 = gb[ 8 + (tid & 7)];
        unsigned gxr2 = gb[16 + (tid & 7)];
        unsigned gxr3 = gb[24 + (tid & 7)];

        // ---- group barrier: relaxed agent spin (no cache-maintenance) ----
        if (tid == 0) {
            while (__hip_atomic_load(mycnt, __ATOMIC_RELAXED,
                                     __HIP_MEMORY_SCOPE_AGENT) < 32 * t)
                __builtin_amdgcn_s_sleep(1);
        }
        __syncthreads();

        const unsigned short* hsrc = (t & 1) ? hb1 : hb0;
        unsigned short*       hdst = (t & 1) ? hb0 : hb1;

        // ---- cooperative h gather: 4096 u64 uncached loads -> LDS ----
        const unsigned long long* hq =
            (const unsigned long long*)hsrc + (size_t)mt * 4096;
        #pragma unroll
        for (int r2 = 0; r2 < 16; r2++) {
            unsigned long long v = __hip_atomic_load(hq + r2 * 256 + tid,
                                                     __ATOMIC_RELAXED,
                                                     __HIP_MEMORY_SCOPE_AGENT);
            hst[r2 * 256 + tid] = v;
        }
        __syncthreads();

        // ---- h @ Wh MFMAs (A from LDS h-stage, B from LDS Wh frags) ----
        f32x4 acc0 = {0.f,0.f,0.f,0.f}, acc1 = acc0;
        #pragma unroll
        for (int khs = 0; khs < KH; khs++) {
            s16x8 a  = *(const s16x8*)(hsl + ((size_t)khs * 64 + lane) * 8);
            s16x8 b0 = *(const s16x8*)(wfl + (((size_t)(n0    ) * KH + khs) * 64 + lane) * 8);
            s16x8 b1 = *(const s16x8*)(wfl + (((size_t)(n0 + 1) * KH + khs) * 64 + lane) * 8);
            acc0 = __builtin_amdgcn_mfma_f32_16x16x32_bf16(a, b0, acc0, 0, 0, 0);
            acc1 = __builtin_amdgcn_mfma_f32_16x16x32_bf16(a, b1, acc1, 0, 0, 0);
        }

        // ---- dump accs to LDS (C/D: col=lane&15, row=quad*4+reg) ----
        int colb = n0 * 16 + l16;
        int rowb = mb * 16 + quad * 4;
        #pragma unroll
        for (int r = 0; r < 4; r++) {
            gl[rowb + r][colb]      = acc0[r];
            gl[rowb + r][colb + 16] = acc1[r];
        }
        __syncthreads();

        // ---- epilogue: gates = gl + gx + bias; LSTM + phased gate ----
        float hn2[2];
        #pragma unroll
        for (int r = 0; r < 2; r++) {
            int j_l = j0 + r;
            float xi = __uint_as_float(r == 0 ? (gxr0 << 16) : (gxr0 & 0xffff0000u));
            float xf = __uint_as_float(r == 0 ? (gxr1 << 16) : (gxr1 & 0xffff0000u));
            float xg = __uint_as_float(r == 0 ? (gxr2 << 16) : (gxr2 & 0xffff0000u));
            float xo = __uint_as_float(r == 0 ? (gxr3 << 16) : (gxr3 & 0xffff0000u));
            float iv = gl[b_l][j_l]      + xi + bi[r];
            float fv = gl[b_l][16 + j_l] + xf + bff[r];
            float gv = gl[b_l][32 + j_l] + xg + bg[r];
            float ov = gl[b_l][48 + j_l] + xo + bo[r];
            iv = 1.f / (1.f + expf(-iv));
            fv = 1.f / (1.f + expf(-fv));
            gv = tanhf(gv);
            ov = 1.f / (1.f + expf(-ov));
            float ct = fv * creg[r] + iv * gv;
            float ht = ov * tanhf(ct);
            float phi = fmodf((float)t - sj[r], tj[r]);
            phi = (phi < 0.f) ? phi + tj[r] : phi;
            phi /= tj[r];
            float kg = (phi < 0.025f) ? 40.f * phi
                     : ((phi < 0.05f) ? 2.f - 40.f * phi : 0.001f * phi);
            creg[r] = kg * ct + (1.f - kg) * creg[r];
            hreg[r] = kg * ht + (1.f - kg) * hreg[r];
            hn2[r] = hreg[r];
        }
        unsigned pv = (unsigned)f2bf(hn2[0]) | ((unsigned)f2bf(hn2[1]) << 16);
        __hip_atomic_store((unsigned*)hdst + pub32, pv, __ATOMIC_RELAXED,
                           __HIP_MEMORY_SCOPE_AGENT);
        if (t == T_STEPS - 1) {
            hplain[(size_t)bG * HID + jG0]     = hn2[0];
            hplain[(size_t)bG * HID + jG0 + 1] = hn2[1];
        }
        __syncthreads();   // drains vmcnt: publish visible at LLC

        if (tid == 0)
            __hip_atomic_fetch_add(mycnt, 1, __ATOMIC_RELAXED,
                                   __HIP_MEMORY_SCOPE_AGENT);
    }
}

// ---------------------------------------------------------------------------
// FALLBACK persistent kernel (R3, proven) — used when ws_size < WS_NEED.
// ---------------------------------------------------------------------------
__global__ __launch_bounds__(256, 1) void plstm_persist(
    const float* __restrict__ x,
    const unsigned short* __restrict__ Wf,
    unsigned short* __restrict__ hb0,
    unsigned short* __restrict__ hb1,
    float* __restrict__ hplain,
    const float* __restrict__ bias,
    const float* __restrict__ tau,
    const float* __restrict__ shift,
    int* __restrict__ cnt)
{
    __shared__ unsigned short wfl[4 * KSTEPS * 64 * 8];
    __shared__ float gl[32][65];

    int tid = threadIdx.x;
    int lane = tid & 63, w = tid >> 6;
    int mt = blockIdx.x & 7, hg = blockIdx.x >> 3;
    int quad = lane >> 4, l16 = lane & 15;
    int mb = w & 1;
    int n0 = (w >> 1) * 2;

    {
        const s16x8* src = (const s16x8*)(Wf + (size_t)(hg * 4) * KSTEPS * 64 * 8);
        s16x8* dst = (s16x8*)wfl;
        #pragma unroll
        for (int i = 0; i < 36; i++)
            dst[i * 256 + tid] = src[i * 256 + tid];
    }

    int b_l  = tid >> 3;
    int j_l0 = (tid & 7) * 2;
    int bG   = mt * 32 + b_l;
    int jG0  = hg * 16 + j_l0;
    float bi[2], bff[2], bg[2], bo[2], tj[2], sj[2];
    #pragma unroll
    for (int r = 0; r < 2; r++) {
        int jG = jG0 + r;
        bi[r] = bias[jG];        bff[r] = bias[512 + jG];
        bg[r] = bias[1024 + jG]; bo[r] = bias[1536 + jG];
        tj[r] = tau[jG];         sj[r] = shift[jG];
    }
    float creg[2] = {0.f, 0.f}, hreg[2] = {0.f, 0.f};
    size_t pub32;
    {
        int mb2  = bG >> 4, khs2 = jG0 >> 5;
        int ln   = (bG & 15) + ((jG0 >> 3) & 3) * 16;
        pub32 = ((((size_t)mb2 * KH + khs2) * 64 + ln) * 8 + (jG0 & 7)) >> 1;
    }
    __syncthreads();

    int rowA = mt * 32 + mb * 16 + l16;
    int mbg  = mt * 2 + mb;
    int* mycnt = cnt + mt * 32;

    for (int t = 0; t < T_STEPS; t++) {
        f32x4 acc0 = {0.f,0.f,0.f,0.f}, acc1 = acc0;
        #pragma unroll
        for (int ks = 0; ks < KX; ks++) {
            int k = ks * 32 + quad * 8;
            int p = k >> 7, f = k & 127;
            const float* sp = x + ((size_t)(rowA * 5 + p) * 256 + t) * 128 + f;
            float4 u0 = *(const float4*)sp;
            float4 u1 = *(const float4*)(sp + 4);
            s16x8 a = pack8(u0, u1);
            s16x8 b0 = *(const s16x8*)(wfl + (((n0    ) * KSTEPS + ks) * 64 + lane) * 8);
            s16x8 b1 = *(const s16x8*)(wfl + (((n0 + 1) * KSTEPS + ks) * 64 + lane) * 8);
            acc0 = __builtin_amdgcn_mfma_f32_16x16x32_bf16(a, b0, acc0, 0, 0, 0);
            acc1 = __builtin_amdgcn_mfma_f32_16x16x32_bf16(a, b1, acc1, 0, 0, 0);
        }

        if (tid == 0) {
            while (__hip_atomic_load(mycnt, __ATOMIC_RELAXED,
                                     __HIP_MEMORY_SCOPE_AGENT) < 32 * t)
                __builtin_amdgcn_s_sleep(1);
        }
        __syncthreads();

        const unsigned short* hsrc = (t & 1) ? hb1 : hb0;
        unsigned short*       hdst = (t & 1) ? hb0 : hb1;

        const unsigned long long* hq =
            (const unsigned long long*)(hsrc + ((size_t)mbg * KH * 64) * 8);
        #pragma unroll
        for (int khs = 0; khs < KH; khs++) {
            union { unsigned long long q[2]; s16x8 v; } a;
            size_t base = ((size_t)khs * 64 + lane) * 2;
            a.q[0] = __hip_atomic_load(hq + base,     __ATOMIC_RELAXED,
                                       __HIP_MEMORY_SCOPE_AGENT);
            a.q[1] = __hip_atomic_load(hq + base + 1, __ATOMIC_RELAXED,
                                       __HIP_MEMORY_SCOPE_AGENT);
            int ks = KX + khs;
            s16x8 b0 = *(const s16x8*)(wfl + (((n0    ) * KSTEPS + ks) * 64 + lane) * 8);
            s16x8 b1 = *(const s16x8*)(wfl + (((n0 + 1) * KSTEPS + ks) * 64 + lane) * 8);
            acc0 = __builtin_amdgcn_mfma_f32_16x16x32_bf16(a.v, b0, acc0, 0, 0, 0);
            acc1 = __builtin_amdgcn_mfma_f32_16x16x32_bf16(a.v, b1, acc1, 0, 0, 0);
        }

        int colb = n0 * 16 + l16;
        int rowb = mb * 16 + quad * 4;
        #pragma unroll
        for (int r = 0; r < 4; r++) {
            gl[rowb + r][colb]      = acc0[r];
            gl[rowb + r][colb + 16] = acc1[r];
        }
        __syncthreads();

        float hn2[2];
        #pragma unroll
        for (int r = 0; r < 2; r++) {
            int j_l = j_l0 + r;
            float iv = gl[b_l][j_l]      + bi[r];
            float fv = gl[b_l][16 + j_l] + bff[r];
            float gv = gl[b_l][32 + j_l] + bg[r];
            float ov = gl[b_l][48 + j_l] + bo[r];
            iv = 1.f / (1.f + expf(-iv));
            fv = 1.f / (1.f + expf(-fv));
            gv = tanhf(gv);
            ov = 1.f / (1.f + expf(-ov));
            float ct = fv * creg[r] + iv * gv;
            float ht = ov * tanhf(ct);
            float phi = fmodf((float)t - sj[r], tj[r]);
            phi = (phi < 0.f) ? phi + tj[r] : phi;
            phi /= tj[r];
            float kg = (phi < 0.025f) ? 40.f * phi
                     : ((phi < 0.05f) ? 2.f - 40.f * phi : 0.001f * phi);
            creg[r] = kg * ct + (1.f - kg) * creg[r];
            hreg[r] = kg * ht + (1.f - kg) * hreg[r];
            hn2[r] = hreg[r];
        }
        unsigned pv = (unsigned)f2bf(hn2[0]) | ((unsigned)f2bf(hn2[1]) << 16);
        __hip_atomic_store((unsigned*)hdst + pub32, pv, __ATOMIC_RELAXED,
                           __HIP_MEMORY_SCOPE_AGENT);
        if (t == T_STEPS - 1) {
            hplain[(size_t)bG * HID + jG0]     = hn2[0];
            hplain[(size_t)bG * HID + jG0 + 1] = hn2[1];
        }
        __syncthreads();

        if (tid == 0)
            __hip_atomic_fetch_add(mycnt, 1, __ATOMIC_RELAXED,
                                   __HIP_MEMORY_SCOPE_AGENT);
    }
}

// ---------------------------------------------------------------------------
// Final FC (512 -> 60) + log_softmax. One wave per batch row.
// ---------------------------------------------------------------------------
__global__ __launch_bounds__(64) void fc_kernel(
    const float* __restrict__ hplain, const float* __restrict__ fcw,
    const float* __restrict__ fcb, float* __restrict__ out)
{
    int b = blockIdx.x, lane = threadIdx.x;
    float logit = -INFINITY;
    if (lane < NCLASS) {
        float s = fcb[lane];
        const float* hp = hplain + (size_t)b * HID;
        #pragma unroll 8
        for (int k = 0; k < HID; k++)
            s += hp[k] * fcw[(size_t)k * NCLASS + lane];
        logit = s;
    }
    float m = logit;
    for (int off = 32; off > 0; off >>= 1)
        m = fmaxf(m, __shfl_xor(m, off, 64));
    float e = (lane < NCLASS) ? expf(logit - m) : 0.f;
    float se = e;
    for (int off = 32; off > 0; off >>= 1)
        se += __shfl_xor(se, off, 64);
    if (lane < NCLASS)
        out[(size_t)b * NCLASS + lane] = logit - m - logf(se);
}

extern "C" void kernel_launch(void* const* d_in, const int* in_sizes, int n_in,
                              void* d_out, int out_size, void* d_ws, size_t ws_size,
                              hipStream_t stream)
{
    const float* x     = (const float*)d_in[0];
    const float* Wx    = (const float*)d_in[1];
    const float* Wh    = (const float*)d_in[2];
    const float* bias  = (const float*)d_in[3];
    const float* tau   = (const float*)d_in[4];
    const float* shift = (const float*)d_in[5];
    const float* fcw   = (const float*)d_in[6];
    const float* fcb   = (const float*)d_in[7];
    float* out = (float*)d_out;
    char* ws = (char*)d_ws;

    int*            cntp   = (int*)ws;
    unsigned short* Wf     = (unsigned short*)(ws + WF_OFF);
    unsigned short* hb0    = (unsigned short*)(ws + HB0_OFF);
    unsigned short* hb1    = (unsigned short*)(ws + HB1_OFF);
    float*          hplain = (float*)(ws + HPL_OFF);
    unsigned short* gxp    = (unsigned short*)(ws + GX_OFF);

    hipMemsetAsync(ws, 0, 1024, stream);                 // counters
    hipMemsetAsync(ws + HB0_OFF, 0, 262144, stream);     // h0 = 0

    pack_w_kernel<<<dim3(1152), dim3(256), 0, stream>>>(Wx, Wh, Wf);

    if (ws_size >= WS_NEED) {
        gx_kernel<<<dim3(32768), dim3(256), 0, stream>>>(x, Wf, gxp);
        plstm_persist2<<<dim3(256), dim3(256), 0, stream>>>(
            gxp, Wf, hb0, hb1, hplain, bias, tau, shift, cntp);
    } else {
        plstm_persist<<<dim3(256), dim3(256), 0, stream>>>(
            x, Wf, hb0, hb1, hplain, bias, tau, shift, cntp);
    }

    fc_kernel<<<dim3(256), dim3(64), 0, stream>>>(hplain, fcw, fcb, out);
}

// Round 5
// 1678.044 us; speedup vs baseline: 1.8839x; 1.8839x over previous
//
#include <hip/hip_runtime.h>
#include <math.h>

// Problem constants
#define T_STEPS 256
#define BATCH   256
#define HID     512
#define DIN     640     // P*F = 5*128
#define NCOL    2048    // 4*H
#define NCLASS  60
#define KSTEPS  36      // 1152 / 32
#define KX      20      // x-part k-steps (640/32)
#define KH      16      // h-part k-steps (512/32)

typedef float f32x4 __attribute__((ext_vector_type(4)));
typedef short s16x8 __attribute__((ext_vector_type(8)));

// ws layout (bytes):
//   [0,        4096)      control: safecnt[8*32] ints @0, fastcnt[8*32] ints @1024,
//                         precnt @2048, xccbuf[256] ints @2176
//   [4096,     4722688)   Wf  bf16 packed weights (128*36*64*8 shorts)
//   [4722688,  4984832)   hb0 bf16 h frag buffer (256 KB)
//   [4984832,  5246976)   hb1 bf16 h frag buffer
//   [5246976,  5771264)   hplain fp32 (256x512)
//   [5771264,  89657344)  xf  bf16 x A-frags [t][mbg][ks][lane][8] (84 MB)
#define WF_OFF   4096
#define HB0_OFF  4722688
#define HB1_OFF  4984832
#define HPL_OFF  5246976
#define XF_OFF   5771264
#define WS_NEED  89657344ULL

__device__ __forceinline__ unsigned short f2bf(float x) {
    union { float f; unsigned u; } v; v.f = x;
    unsigned r = v.u + 0x7fffu + ((v.u >> 16) & 1u);   // round-to-nearest-even
    return (unsigned short)(r >> 16);
}

__device__ __forceinline__ s16x8 pack8(float4 a, float4 b) {
    s16x8 r;
    r[0] = (short)f2bf(a.x); r[1] = (short)f2bf(a.y);
    r[2] = (short)f2bf(a.z); r[3] = (short)f2bf(a.w);
    r[4] = (short)f2bf(b.x); r[5] = (short)f2bf(b.y);
    r[6] = (short)f2bf(b.z); r[7] = (short)f2bf(b.w);
    return r;
}

// ---------------------------------------------------------------------------
// Pack [Wx; Wh] (1152 x 2048 fp32) into bf16 B-fragment-linear layout.
// ---------------------------------------------------------------------------
__global__ __launch_bounds__(256) void pack_w_kernel(
    const float* __restrict__ Wx, const float* __restrict__ Wh,
    unsigned short* __restrict__ Wf)
{
    int g = blockIdx.x * 256 + threadIdx.x;      // [0, 128*36*64)
    int nb  = g / (KSTEPS * 64);
    int rem = g - nb * (KSTEPS * 64);
    int ks = rem >> 6;
    int lane = rem & 63;
    int gate = nb & 3, hg = nb >> 2;
    int n = gate * 512 + hg * 16 + (lane & 15);
    int kbase = ks * 32 + (lane >> 4) * 8;
    s16x8 frag;
    #pragma unroll
    for (int j = 0; j < 8; j++) {
        int k = kbase + j;
        float v = (k < DIN) ? Wx[(size_t)k * NCOL + n]
                            : Wh[(size_t)(k - DIN) * NCOL + n];
        frag[j] = (short)f2bf(v);
    }
    *(s16x8*)(Wf + (size_t)g * 8) = frag;
}

// ---------------------------------------------------------------------------
// Pre-convert x to bf16 A-fragment layout: xf[((t*16+mbg)*20+ks)*64+lane][8]
// row = mbg*16 + (lane&15), k = ks*32 + (lane>>4)*8 + j. One pass over x.
// ---------------------------------------------------------------------------
__global__ __launch_bounds__(256) void xf_kernel(
    const float* __restrict__ x, unsigned short* __restrict__ xf)
{
    int bid = blockIdx.x;            // t*16 + mbg
    int t = bid >> 4, mbg = bid & 15;
    for (int it = threadIdx.x; it < 1280; it += 256) {
        int ks = it >> 6, lane = it & 63;
        int row = mbg * 16 + (lane & 15);
        int k = ks * 32 + (lane >> 4) * 8;
        int p = k >> 7, f = k & 127;
        const float* sp = x + ((size_t)(row * 5 + p) * 256 + t) * 128 + f;
        float4 u0 = *(const float4*)sp;
        float4 u1 = *(const float4*)(sp + 4);
        s16x8 o = pack8(u0, u1);
        *(s16x8*)(xf + ((size_t)bid * 1280 + it) * 8) = o;
    }
}

// ---------------------------------------------------------------------------
// Persistent phased-LSTM. 256 WGs x 256 thr, 1 WG/CU. WG=(mt=bid&7, hg=bid>>3).
// Full Wf slice (36 ksteps) in LDS. Per-group protocol chosen at runtime:
//   FAST (all 32 members share an XCD, verified via HW_REG_XCC_ID): h exchange
//     through the XCD's L2 — plain write-through stores, buffer_inv (L1-only)
//     + plain coalesced loads, plain global_atomic_add (L2-executed) barrier.
//   SAFE (fallback, R3-proven): relaxed agent-scope atomics at LLC.
// ---------------------------------------------------------------------------
__global__ __launch_bounds__(256, 1) void plstm_persist3(
    const unsigned short* __restrict__ xf,
    const unsigned short* __restrict__ Wf,
    unsigned short* __restrict__ hb0,
    unsigned short* __restrict__ hb1,
    float* __restrict__ hplain,
    const float* __restrict__ bias,
    const float* __restrict__ tau,
    const float* __restrict__ shift,
    int* __restrict__ ctl)
{
    __shared__ unsigned short wfl[4 * KSTEPS * 64 * 8];  // 147456 B
    __shared__ float gl[32][65];                          // 8320 B
    __shared__ int protflag;

    int tid = threadIdx.x;
    int lane = tid & 63, w = tid >> 6;
    int bid = blockIdx.x;
    int mt = bid & 7, hg = bid >> 3;
    int quad = lane >> 4, l16 = lane & 15;
    int mb = w & 1;
    int n0 = (w >> 1) * 2;

    // --- XCD-uniformity handshake (one-time) ---
    int xcc = __builtin_amdgcn_s_getreg((31 << 11) | (0 << 6) | 20); // HW_REG_XCC_ID
    if (tid == 0) {
        __hip_atomic_store(&ctl[544 + bid], xcc + 1, __ATOMIC_RELAXED,
                           __HIP_MEMORY_SCOPE_AGENT);
        asm volatile("s_waitcnt vmcnt(0)" ::: "memory");
        __hip_atomic_fetch_add(&ctl[512], 1, __ATOMIC_RELAXED,
                               __HIP_MEMORY_SCOPE_AGENT);
        while (__hip_atomic_load(&ctl[512], __ATOMIC_RELAXED,
                                 __HIP_MEMORY_SCOPE_AGENT) < 256)
            __builtin_amdgcn_s_sleep(1);
    }

    // --- stage weight slice into LDS (overlaps handshake) ---
    {
        const s16x8* src = (const s16x8*)(Wf + (size_t)(hg * 4) * KSTEPS * 64 * 8);
        s16x8* dst = (s16x8*)wfl;
        #pragma unroll
        for (int i = 0; i < 36; i++)
            dst[i * 256 + tid] = src[i * 256 + tid];
    }
    __syncthreads();

    if (w == 0) {
        int pred = 1;
        if (lane < 32) {
            int v = __hip_atomic_load(&ctl[544 + mt + 8 * lane], __ATOMIC_RELAXED,
                                      __HIP_MEMORY_SCOPE_AGENT);
            pred = (v == xcc + 1);
        }
        unsigned long long bal = __ballot(pred);
        if (lane == 0) protflag = (bal == ~0ull) ? 1 : 0;
    }
    __syncthreads();
    int fast = protflag;

    // --- per-thread epilogue constants + register state (2 cells) ---
    int b_l = tid >> 3;
    int j0  = (tid & 7) * 2;
    int bG  = mt * 32 + b_l;
    int jG0 = hg * 16 + j0;
    float bi[2], bff[2], bg[2], bo[2], tj[2], sj[2];
    #pragma unroll
    for (int r = 0; r < 2; r++) {
        int jG = jG0 + r;
        bi[r] = bias[jG];        bff[r] = bias[512 + jG];
        bg[r] = bias[1024 + jG]; bo[r] = bias[1536 + jG];
        tj[r] = tau[jG];         sj[r] = shift[jG];
    }
    float creg[2] = {0.f, 0.f}, hreg[2] = {0.f, 0.f};
    size_t pub32;
    {
        int mb2 = bG >> 4, khs2 = jG0 >> 5;
        int ln  = (bG & 15) + ((jG0 >> 3) & 3) * 16;
        pub32 = ((((size_t)mb2 * KH + khs2) * 64 + ln) * 8 + (jG0 & 7)) >> 1;
    }

    int mbg = mt * 2 + mb;
    volatile int* fcv = (volatile int*)&ctl[256 + mt * 32];
    unsigned long long fca = (unsigned long long)(ctl + 256 + mt * 32);
    int* scnt = &ctl[mt * 32];

    for (int t = 0; t < T_STEPS; t++) {
        // ---- x phase: A-frags from xf (plain cached, coalesced) + MFMA ----
        f32x4 acc0 = {0.f, 0.f, 0.f, 0.f}, acc1 = acc0;
        const s16x8* xa = (const s16x8*)xf + ((size_t)t * 16 + mbg) * KX * 64;
        #pragma unroll
        for (int ks = 0; ks < KX; ks++) {
            s16x8 a  = xa[ks * 64 + lane];
            s16x8 b0 = *(const s16x8*)(wfl + (((n0    ) * KSTEPS + ks) * 64 + lane) * 8);
            s16x8 b1 = *(const s16x8*)(wfl + (((n0 + 1) * KSTEPS + ks) * 64 + lane) * 8);
            acc0 = __builtin_amdgcn_mfma_f32_16x16x32_bf16(a, b0, acc0, 0, 0, 0);
            acc1 = __builtin_amdgcn_mfma_f32_16x16x32_bf16(a, b1, acc1, 0, 0, 0);
        }

        // ---- group barrier wait ----
        if (tid == 0) {
            if (fast) {
                int v;
                do {
                    asm volatile("buffer_inv" ::: "memory");  // drop CU L1
                    v = *fcv;                                  // plain load -> L2
                } while (v < 32 * t);
            } else {
                while (__hip_atomic_load(scnt, __ATOMIC_RELAXED,
                                         __HIP_MEMORY_SCOPE_AGENT) < 32 * t)
                    __builtin_amdgcn_s_sleep(1);
            }
        }
        __syncthreads();

        const unsigned short* hsrc = (t & 1) ? hb1 : hb0;
        unsigned short*       hdst = (t & 1) ? hb0 : hb1;

        // ---- h phase ----
        if (fast) {
            asm volatile("buffer_inv" ::: "memory");   // per-wave L1 invalidate
            const s16x8* hs = (const s16x8*)hsrc + (size_t)mbg * KH * 64;
            #pragma unroll
            for (int khs = 0; khs < KH; khs++) {
                s16x8 a  = hs[khs * 64 + lane];
                int ks = KX + khs;
                s16x8 b0 = *(const s16x8*)(wfl + (((n0    ) * KSTEPS + ks) * 64 + lane) * 8);
                s16x8 b1 = *(const s16x8*)(wfl + (((n0 + 1) * KSTEPS + ks) * 64 + lane) * 8);
                acc0 = __builtin_amdgcn_mfma_f32_16x16x32_bf16(a, b0, acc0, 0, 0, 0);
                acc1 = __builtin_amdgcn_mfma_f32_16x16x32_bf16(a, b1, acc1, 0, 0, 0);
            }
        } else {
            const unsigned long long* hq =
                (const unsigned long long*)(hsrc + ((size_t)mbg * KH * 64) * 8);
            #pragma unroll
            for (int khs = 0; khs < KH; khs++) {
                union { unsigned long long q[2]; s16x8 v; } a;
                size_t base = ((size_t)khs * 64 + lane) * 2;
                a.q[0] = __hip_atomic_load(hq + base,     __ATOMIC_RELAXED,
                                           __HIP_MEMORY_SCOPE_AGENT);
                a.q[1] = __hip_atomic_load(hq + base + 1, __ATOMIC_RELAXED,
                                           __HIP_MEMORY_SCOPE_AGENT);
                int ks = KX + khs;
                s16x8 b0 = *(const s16x8*)(wfl + (((n0    ) * KSTEPS + ks) * 64 + lane) * 8);
                s16x8 b1 = *(const s16x8*)(wfl + (((n0 + 1) * KSTEPS + ks) * 64 + lane) * 8);
                acc0 = __builtin_amdgcn_mfma_f32_16x16x32_bf16(a.v, b0, acc0, 0, 0, 0);
                acc1 = __builtin_amdgcn_mfma_f32_16x16x32_bf16(a.v, b1, acc1, 0, 0, 0);
            }
        }

        // ---- dump accs to LDS (C/D: col=lane&15, row=quad*4+reg) ----
        int colb = n0 * 16 + l16;
        int rowb = mb * 16 + quad * 4;
        #pragma unroll
        for (int r = 0; r < 4; r++) {
            gl[rowb + r][colb]      = acc0[r];
            gl[rowb + r][colb + 16] = acc1[r];
        }
        __syncthreads();

        // ---- epilogue: activations + cell + phased gate ----
        float hn2[2];
        #pragma unroll
        for (int r = 0; r < 2; r++) {
            int j_l = j0 + r;
            float iv = gl[b_l][j_l]      + bi[r];
            float fv = gl[b_l][16 + j_l] + bff[r];
            float gv = gl[b_l][32 + j_l] + bg[r];
            float ov = gl[b_l][48 + j_l] + bo[r];
            iv = 1.f / (1.f + expf(-iv));
            fv = 1.f / (1.f + expf(-fv));
            gv = tanhf(gv);
            ov = 1.f / (1.f + expf(-ov));
            float ct = fv * creg[r] + iv * gv;
            float ht = ov * tanhf(ct);
            float phi = fmodf((float)t - sj[r], tj[r]);
            phi = (phi < 0.f) ? phi + tj[r] : phi;
            phi /= tj[r];
            float kg = (phi < 0.025f) ? 40.f * phi
                     : ((phi < 0.05f) ? 2.f - 40.f * phi : 0.001f * phi);
            creg[r] = kg * ct + (1.f - kg) * creg[r];
            hreg[r] = kg * ht + (1.f - kg) * hreg[r];
            hn2[r] = hreg[r];
        }
        unsigned pv = (unsigned)f2bf(hn2[0]) | ((unsigned)f2bf(hn2[1]) << 16);
        if (fast) {
            ((unsigned*)hdst)[pub32] = pv;              // write-through to L2
        } else {
            __hip_atomic_store((unsigned*)hdst + pub32, pv, __ATOMIC_RELAXED,
                               __HIP_MEMORY_SCOPE_AGENT);
        }
        if (t == T_STEPS - 1) {
            hplain[(size_t)bG * HID + jG0]     = hn2[0];
            hplain[(size_t)bG * HID + jG0 + 1] = hn2[1];
        }
        __syncthreads();   // drains vmcnt: publish visible at coherence point

        // ---- group barrier arrive ----
        if (tid == 0) {
            if (fast) {
                int one = 1;
                asm volatile("global_atomic_add %0, %1, off"
                             :: "v"(fca), "v"(one) : "memory");  // L2-executed
            } else {
                __hip_atomic_fetch_add(scnt, 1, __ATOMIC_RELAXED,
                                       __HIP_MEMORY_SCOPE_AGENT);
            }
        }
    }
}

// ---------------------------------------------------------------------------
// FALLBACK persistent kernel (R3, proven) — used when ws_size < WS_NEED.
// ---------------------------------------------------------------------------
__global__ __launch_bounds__(256, 1) void plstm_persist(
    const float* __restrict__ x,
    const unsigned short* __restrict__ Wf,
    unsigned short* __restrict__ hb0,
    unsigned short* __restrict__ hb1,
    float* __restrict__ hplain,
    const float* __restrict__ bias,
    const float* __restrict__ tau,
    const float* __restrict__ shift,
    int* __restrict__ cnt)
{
    __shared__ unsigned short wfl[4 * KSTEPS * 64 * 8];
    __shared__ float gl[32][65];

    int tid = threadIdx.x;
    int lane = tid & 63, w = tid >> 6;
    int mt = blockIdx.x & 7, hg = blockIdx.x >> 3;
    int quad = lane >> 4, l16 = lane & 15;
    int mb = w & 1;
    int n0 = (w >> 1) * 2;

    {
        const s16x8* src = (const s16x8*)(Wf + (size_t)(hg * 4) * KSTEPS * 64 * 8);
        s16x8* dst = (s16x8*)wfl;
        #pragma unroll
        for (int i = 0; i < 36; i++)
            dst[i * 256 + tid] = src[i * 256 + tid];
    }

    int b_l  = tid >> 3;
    int j_l0 = (tid & 7) * 2;
    int bG   = mt * 32 + b_l;
    int jG0  = hg * 16 + j_l0;
    float bi[2], bff[2], bg[2], bo[2], tj[2], sj[2];
    #pragma unroll
    for (int r = 0; r < 2; r++) {
        int jG = jG0 + r;
        bi[r] = bias[jG];        bff[r] = bias[512 + jG];
        bg[r] = bias[1024 + jG]; bo[r] = bias[1536 + jG];
        tj[r] = tau[jG];         sj[r] = shift[jG];
    }
    float creg[2] = {0.f, 0.f}, hreg[2] = {0.f, 0.f};
    size_t pub32;
    {
        int mb2  = bG >> 4, khs2 = jG0 >> 5;
        int ln   = (bG & 15) + ((jG0 >> 3) & 3) * 16;
        pub32 = ((((size_t)mb2 * KH + khs2) * 64 + ln) * 8 + (jG0 & 7)) >> 1;
    }
    __syncthreads();

    int rowA = mt * 32 + mb * 16 + l16;
    int mbg  = mt * 2 + mb;
    int* mycnt = cnt + mt * 32;

    for (int t = 0; t < T_STEPS; t++) {
        f32x4 acc0 = {0.f,0.f,0.f,0.f}, acc1 = acc0;
        #pragma unroll
        for (int ks = 0; ks < KX; ks++) {
            int k = ks * 32 + quad * 8;
            int p = k >> 7, f = k & 127;
            const float* sp = x + ((size_t)(rowA * 5 + p) * 256 + t) * 128 + f;
            float4 u0 = *(const float4*)sp;
            float4 u1 = *(const float4*)(sp + 4);
            s16x8 a = pack8(u0, u1);
            s16x8 b0 = *(const s16x8*)(wfl + (((n0    ) * KSTEPS + ks) * 64 + lane) * 8);
            s16x8 b1 = *(const s16x8*)(wfl + (((n0 + 1) * KSTEPS + ks) * 64 + lane) * 8);
            acc0 = __builtin_amdgcn_mfma_f32_16x16x32_bf16(a, b0, acc0, 0, 0, 0);
            acc1 = __builtin_amdgcn_mfma_f32_16x16x32_bf16(a, b1, acc1, 0, 0, 0);
        }

        if (tid == 0) {
            while (__hip_atomic_load(mycnt, __ATOMIC_RELAXED,
                                     __HIP_MEMORY_SCOPE_AGENT) < 32 * t)
                __builtin_amdgcn_s_sleep(1);
        }
        __syncthreads();

        const unsigned short* hsrc = (t & 1) ? hb1 : hb0;
        unsigned short*       hdst = (t & 1) ? hb0 : hb1;

        const unsigned long long* hq =
            (const unsigned long long*)(hsrc + ((size_t)mbg * KH * 64) * 8);
        #pragma unroll
        for (int khs = 0; khs < KH; khs++) {
            union { unsigned long long q[2]; s16x8 v; } a;
            size_t base = ((size_t)khs * 64 + lane) * 2;
            a.q[0] = __hip_atomic_load(hq + base,     __ATOMIC_RELAXED,
                                       __HIP_MEMORY_SCOPE_AGENT);
            a.q[1] = __hip_atomic_load(hq + base + 1, __ATOMIC_RELAXED,
                                       __HIP_MEMORY_SCOPE_AGENT);
            int ks = KX + khs;
            s16x8 b0 = *(const s16x8*)(wfl + (((n0    ) * KSTEPS + ks) * 64 + lane) * 8);
            s16x8 b1 = *(const s16x8*)(wfl + (((n0 + 1) * KSTEPS + ks) * 64 + lane) * 8);
            acc0 = __builtin_amdgcn_mfma_f32_16x16x32_bf16(a.v, b0, acc0, 0, 0, 0);
            acc1 = __builtin_amdgcn_mfma_f32_16x16x32_bf16(a.v, b1, acc1, 0, 0, 0);
        }

        int colb = n0 * 16 + l16;
        int rowb = mb * 16 + quad * 4;
        #pragma unroll
        for (int r = 0; r < 4; r++) {
            gl[rowb + r][colb]      = acc0[r];
            gl[rowb + r][colb + 16] = acc1[r];
        }
        __syncthreads();

        float hn2[2];
        #pragma unroll
        for (int r = 0; r < 2; r++) {
            int j_l = j_l0 + r;
            float iv = gl[b_l][j_l]      + bi[r];
            float fv = gl[b_l][16 + j_l] + bff[r];
            float gv = gl[b_l][32 + j_l] + bg[r];
            float ov = gl[b_l][48 + j_l] + bo[r];
            iv = 1.f / (1.f + expf(-iv));
            fv = 1.f / (1.f + expf(-fv));
            gv = tanhf(gv);
            ov = 1.f / (1.f + expf(-ov));
            float ct = fv * creg[r] + iv * gv;
            float ht = ov * tanhf(ct);
            float phi = fmodf((float)t - sj[r], tj[r]);
            phi = (phi < 0.f) ? phi + tj[r] : phi;
            phi /= tj[r];
            float kg = (phi < 0.025f) ? 40.f * phi
                     : ((phi < 0.05f) ? 2.f - 40.f * phi : 0.001f * phi);
            creg[r] = kg * ct + (1.f - kg) * creg[r];
            hreg[r] = kg * ht + (1.f - kg) * hreg[r];
            hn2[r] = hreg[r];
        }
        unsigned pv = (unsigned)f2bf(hn2[0]) | ((unsigned)f2bf(hn2[1]) << 16);
        __hip_atomic_store((unsigned*)hdst + pub32, pv, __ATOMIC_RELAXED,
                           __HIP_MEMORY_SCOPE_AGENT);
        if (t == T_STEPS - 1) {
            hplain[(size_t)bG * HID + jG0]     = hn2[0];
            hplain[(size_t)bG * HID + jG0 + 1] = hn2[1];
        }
        __syncthreads();

        if (tid == 0)
            __hip_atomic_fetch_add(mycnt, 1, __ATOMIC_RELAXED,
                                   __HIP_MEMORY_SCOPE_AGENT);
    }
}

// ---------------------------------------------------------------------------
// Final FC (512 -> 60) + log_softmax. One wave per batch row.
// ---------------------------------------------------------------------------
__global__ __launch_bounds__(64) void fc_kernel(
    const float* __restrict__ hplain, const float* __restrict__ fcw,
    const float* __restrict__ fcb, float* __restrict__ out)
{
    int b = blockIdx.x, lane = threadIdx.x;
    float logit = -INFINITY;
    if (lane < NCLASS) {
        float s = fcb[lane];
        const float* hp = hplain + (size_t)b * HID;
        #pragma unroll 8
        for (int k = 0; k < HID; k++)
            s += hp[k] * fcw[(size_t)k * NCLASS + lane];
        logit = s;
    }
    float m = logit;
    for (int off = 32; off > 0; off >>= 1)
        m = fmaxf(m, __shfl_xor(m, off, 64));
    float e = (lane < NCLASS) ? expf(logit - m) : 0.f;
    float se = e;
    for (int off = 32; off > 0; off >>= 1)
        se += __shfl_xor(se, off, 64);
    if (lane < NCLASS)
        out[(size_t)b * NCLASS + lane] = logit - m - logf(se);
}

extern "C" void kernel_launch(void* const* d_in, const int* in_sizes, int n_in,
                              void* d_out, int out_size, void* d_ws, size_t ws_size,
                              hipStream_t stream)
{
    const float* x     = (const float*)d_in[0];
    const float* Wx    = (const float*)d_in[1];
    const float* Wh    = (const float*)d_in[2];
    const float* bias  = (const float*)d_in[3];
    const float* tau   = (const float*)d_in[4];
    const float* shift = (const float*)d_in[5];
    const float* fcw   = (const float*)d_in[6];
    const float* fcb   = (const float*)d_in[7];
    float* out = (float*)d_out;
    char* ws = (char*)d_ws;

    int*            ctl    = (int*)ws;
    unsigned short* Wf     = (unsigned short*)(ws + WF_OFF);
    unsigned short* hb0    = (unsigned short*)(ws + HB0_OFF);
    unsigned short* hb1    = (unsigned short*)(ws + HB1_OFF);
    float*          hplain = (float*)(ws + HPL_OFF);
    unsigned short* xfb    = (unsigned short*)(ws + XF_OFF);

    hipMemsetAsync(ws, 0, 4096, stream);                 // control block
    hipMemsetAsync(ws + HB0_OFF, 0, 262144, stream);     // h0 = 0

    pack_w_kernel<<<dim3(1152), dim3(256), 0, stream>>>(Wx, Wh, Wf);

    if (ws_size >= WS_NEED) {
        xf_kernel<<<dim3(4096), dim3(256), 0, stream>>>(x, xfb);
        plstm_persist3<<<dim3(256), dim3(256), 0, stream>>>(
            xfb, Wf, hb0, hb1, hplain, bias, tau, shift, ctl);
    } else {
        plstm_persist<<<dim3(256), dim3(256), 0, stream>>>(
            x, Wf, hb0, hb1, hplain, bias, tau, shift, ctl);
    }

    fc_kernel<<<dim3(256), dim3(64), 0, stream>>>(hplain, fcw, fcb, out);
}